// Round 1
// baseline (215.641 us; speedup 1.0000x reference)
//
#include <hip/hip_runtime.h>
#include <hip/hip_bf16.h>
#include <math.h>

#define MAXN    32
#define NPTS    16384
#define NPSI    65              // 2*MAXN+1 feature dim
#define KPAD    96              // 3 k-steps of 32 for mfma 16x16x32
#define RSTRIDE 104             // ushorts per psi row (208 B, 16B-aligned)
#define BT      64              // output tile edge per block
#define ROWB    (RSTRIDE * 2)   // 208 bytes/row
#define PANELB  (BT * ROWB)     // 13312 bytes per 64-row panel

typedef __attribute__((ext_vector_type(8))) short  bf16x8;
typedef __attribute__((ext_vector_type(4))) float  f32x4;

__device__ inline ushort f2bf(float f) {
    union { float f; unsigned u; } v; v.f = f;
    unsigned u = v.u;
    u += 0x7FFFu + ((u >> 16) & 1u);   // round-to-nearest-even
    return (ushort)(u >> 16);
}

// ---------------- kernel 1: psi rows (bf16, padded) into workspace ----------
__global__ __launch_bounds__(256) void psi_kernel(
    const float* __restrict__ xs, const float* __restrict__ logits,
    ushort* __restrict__ psi)
{
    int pt = blockIdx.x * blockDim.x + threadIdx.x;
    if (pt >= NPTS) return;

    float x = xs[pt];
    x = fminf(1.0f, fmaxf(-1.0f, x));
    float s = sqrtf(fmaxf(0.0f, 1.0f - x * x));

    // softmax over 33 logits (redundant per thread; trivial)
    float m = -3.4e38f;
    #pragma unroll
    for (int n = 0; n <= MAXN; ++n) m = fmaxf(m, logits[n]);
    float sum = 0.0f;
    #pragma unroll
    for (int n = 0; n <= MAXN; ++n) sum += __expf(logits[n] - m);
    float inv = 1.0f / sum;

    ushort tmp[RSTRIDE];
    tmp[0] = f2bf(sqrtf(__expf(logits[0] - m) * inv));
    float Tm1 = 1.0f, T = x;        // T_0, T_1
    float Um1 = 1.0f, U = 2.0f * x; // U_0, U_1
    float tx = 2.0f * x;
    #pragma unroll
    for (int n = 1; n <= MAXN; ++n) {
        float swn = sqrtf(__expf(logits[n] - m) * inv);
        tmp[2 * n - 1] = f2bf(swn * T);
        tmp[2 * n]     = f2bf(swn * (s * Um1));
        float Tn = tx * T - Tm1; Tm1 = T; T = Tn;
        float Un = tx * U - Um1; Um1 = U; U = Un;
    }
    #pragma unroll
    for (int k = NPSI; k < RSTRIDE; ++k) tmp[k] = 0;

    // 8B vector stores of the whole row
    unsigned long long* dst = (unsigned long long*)(psi + (size_t)pt * RSTRIDE);
    const unsigned long long* src = (const unsigned long long*)tmp;
    #pragma unroll
    for (int k = 0; k < RSTRIDE / 4; ++k) dst[k] = src[k];
}

// ---------------- kernel 2: gram = psi @ psi^T, 64x64 tile per block --------
__device__ inline void load_lds16(const void* g, void* l) {
    __builtin_amdgcn_global_load_lds(
        (const __attribute__((address_space(1))) unsigned*)g,
        (__attribute__((address_space(3))) unsigned*)l, 16, 0, 0);
}

__global__ __launch_bounds__(256) void gram_kernel(
    const ushort* __restrict__ psi, float* __restrict__ out)
{
    __shared__ ushort lds[2 * BT * RSTRIDE];   // A panel rows 0..63, B panel rows 64..127

    const int tid  = threadIdx.x;
    const int w    = tid >> 6;     // wave 0..3
    const int lane = tid & 63;
    const int bi   = blockIdx.y;
    const int bj   = blockIdx.x;

    // stage 2 x 13312 B = 26 chunks of 1 KiB (64 lanes x 16 B each)
    {
        const char* gA = (const char*)(psi + (size_t)bi * BT * RSTRIDE);
        const char* gB = (const char*)(psi + (size_t)bj * BT * RSTRIDE);
        char* lbase = (char*)lds;
        for (int q = w; q < 26; q += 4) {
            const char* src = (q < 13) ? (gA + q * 1024) : (gB + (q - 13) * 1024);
            load_lds16(src + lane * 16, lbase + q * 1024);
        }
    }
    __syncthreads();

    const int lr = lane & 15;          // A row / B col within 16-tile
    const int lk = (lane >> 4) * 8;    // k offset within 32-k-step

    const ushort* aBase = lds + (w * 16 + lr) * RSTRIDE;
    const ushort* bBase = lds + (BT + lr) * RSTRIDE;

    f32x4 acc[4];
    #pragma unroll
    for (int c = 0; c < 4; ++c) acc[c] = (f32x4){0.f, 0.f, 0.f, 0.f};

    #pragma unroll
    for (int ks = 0; ks < 3; ++ks) {
        bf16x8 a = *(const bf16x8*)(aBase + ks * 32 + lk);
        #pragma unroll
        for (int c = 0; c < 4; ++c) {
            bf16x8 b = *(const bf16x8*)(bBase + c * 16 * RSTRIDE + ks * 32 + lk);
            acc[c] = __builtin_amdgcn_mfma_f32_16x16x32_bf16(a, b, acc[c], 0, 0, 0);
        }
    }

    // C/D layout: col = lane&15, row = 4*(lane>>4) + reg
    const int r0 = (lane >> 4) * 4;
    #pragma unroll
    for (int r = 0; r < 4; ++r) {
        size_t rowOff = (size_t)(bi * BT + w * 16 + r0 + r) * NPTS + (size_t)bj * BT + lr;
        #pragma unroll
        for (int c = 0; c < 4; ++c) {
            out[rowOff + c * 16] = acc[c][r];
        }
    }
}

extern "C" void kernel_launch(void* const* d_in, const int* in_sizes, int n_in,
                              void* d_out, int out_size, void* d_ws, size_t ws_size,
                              hipStream_t stream) {
    const float* xs     = (const float*)d_in[0];
    const float* logits = (const float*)d_in[1];
    float* out          = (float*)d_out;
    ushort* psi         = (ushort*)d_ws;   // NPTS * RSTRIDE * 2 = 3.4 MB

    psi_kernel<<<NPTS / 256, 256, 0, stream>>>(xs, logits, psi);

    dim3 grid(NPTS / BT, NPTS / BT);
    gram_kernel<<<grid, 256, 0, stream>>>(psi, out);
}